// Round 4
// baseline (358.086 us; speedup 1.0000x reference)
//
#include <hip/hip_runtime.h>

#define T_SEQ 4096
#define C_EMB 2048
#define NH 16
#define NKV 4
#define HD 128

typedef short bf16x8 __attribute__((ext_vector_type(8)));
typedef float f32x4 __attribute__((ext_vector_type(4)));
typedef unsigned short u16x4 __attribute__((ext_vector_type(4)));

__device__ inline unsigned short f2bf(float f) {
    unsigned int u = __float_as_uint(f);
    unsigned int r = (u + 0x7FFFu + ((u >> 16) & 1u)) >> 16;
    return (unsigned short)r;
}

// async global->LDS 16B per lane; lds base must be wave-uniform (lane*16 auto-added)
__device__ __forceinline__ void async_cp16(const unsigned short* g, unsigned short* l) {
    __builtin_amdgcn_global_load_lds((const __attribute__((address_space(1))) unsigned int*)g,
                                     (__attribute__((address_space(3))) unsigned int*)l,
                                     16, 0, 0);
}

// ---------------- fp32 -> bf16 elementwise ----------------
__global__ __launch_bounds__(256) void cvt_bf16(const float* __restrict__ in,
                                                unsigned short* __restrict__ out, int n) {
    int i = (blockIdx.x * 256 + threadIdx.x) * 4;
    if (i >= n) return;
    float4 f = *(const float4*)(&in[i]);
    u16x4 o;
    o.x = f2bf(f.x); o.y = f2bf(f.y); o.z = f2bf(f.z); o.w = f2bf(f.w);
    *(u16x4*)(&out[i]) = o;
}

// ---------------- merged weight transposes: 4 matrices in one launch ----------------
__global__ __launch_bounds__(256) void transpose_all(const float* __restrict__ wq,
                                                     const float* __restrict__ wk,
                                                     const float* __restrict__ wv,
                                                     const float* __restrict__ wo,
                                                     unsigned short* __restrict__ wqkvT,
                                                     unsigned short* __restrict__ woT) {
    __shared__ float tile[32][33];
    int z = blockIdx.z;
    const float* in;
    unsigned short* out;
    int ld_in;
    if (z == 0)      { in = wq; out = wqkvT;                         ld_in = 2048; }
    else if (z == 1) { in = wk; out = wqkvT + (size_t)2048 * 2048;   ld_in = 512;  }
    else if (z == 2) { in = wv; out = wqkvT + (size_t)2560 * 2048;   ld_in = 512;  }
    else             { in = wo; out = woT;                           ld_in = 2048; }
    if ((z == 1 || z == 2) && blockIdx.x >= 16) return;

    int x = blockIdx.x * 32 + threadIdx.x;
    for (int i = threadIdx.y; i < 32; i += 8) {
        int y = blockIdx.y * 32 + i;
        tile[i][threadIdx.x] = in[(size_t)y * ld_in + x];
    }
    __syncthreads();
    int xo = blockIdx.y * 32 + threadIdx.x;
    for (int i = threadIdx.y; i < 32; i += 8) {
        int yo = blockIdx.x * 32 + i;
        out[(size_t)yo * 2048 + xo] = f2bf(tile[threadIdx.x][i]);
    }
}

// ==== Fused QKV projection + RoPE + RMSNorm + V-transpose ====
// v8: 128x128 tile, BK=32, THREE-buffer LDS rotation with counted vmcnt (T4):
// prefetch issue distance = 2 tiles, s_waitcnt vmcnt(4) + raw s_barrier per iter
// (never vmcnt(0) in the main loop) so global_load_lds stays in flight across
// barriers -> L2/HBM latency off the critical path. 48KB LDS -> 3 blocks/CU.
__global__ __launch_bounds__(256, 3) void gemm_qkv(const unsigned short* __restrict__ A,
                                                   const unsigned short* __restrict__ Bt,
                                                   const float* __restrict__ cosb,
                                                   const float* __restrict__ sinb,
                                                   unsigned short* __restrict__ Qn,
                                                   unsigned short* __restrict__ Kn,
                                                   unsigned short* __restrict__ Vt) {
    __shared__ __align__(16) unsigned short As[3][128 * 32];
    __shared__ __align__(16) unsigned short Bs[3][128 * 32];
    const int K = 2048;
    int t = threadIdx.x;
    int w = t >> 6, lane = t & 63;
    int ln = lane & 15, q = lane >> 4;
    int wm = w * 32;
    int m0 = blockIdx.y * 128, n0 = blockIdx.x * 128;

    f32x4 acc[2][8] = {};

    auto stage = [&](int b, int k0) {
#pragma unroll
        for (int s = 0; s < 2; ++s) {
            int L = s * 256 + t;
            int r = L >> 2;
            int c = (L & 3) ^ ((L >> 4) & 3);
            async_cp16(&A[(size_t)(m0 + r) * K + k0 + c * 8], &As[b][s * 2048 + w * 512]);
            async_cp16(&Bt[(size_t)(n0 + r) * K + k0 + c * 8], &Bs[b][s * 2048 + w * 512]);
        }
    };

    stage(0, 0);
    stage(1, 32);

    int bc = 0;
    for (int it = 0; it < 64; ++it) {
        // wait for own current-tile loads (4 newest = next tile may stay in flight)
        if (it < 63) asm volatile("s_waitcnt vmcnt(4)" ::: "memory");
        else         asm volatile("s_waitcnt vmcnt(0)" ::: "memory");
        __builtin_amdgcn_s_barrier();
        __builtin_amdgcn_sched_barrier(0);
        if (it < 62) {
            int bn = bc + 2; if (bn >= 3) bn -= 3;
            stage(bn, (it + 2) * 32);
        }
        int cs = (q ^ ((ln >> 2) & 3)) * 8;
        bf16x8 af[2], bfr[8];
#pragma unroll
        for (int i = 0; i < 2; ++i) af[i] = *(const bf16x8*)(&As[bc][(wm + i * 16 + ln) * 32 + cs]);
#pragma unroll
        for (int j = 0; j < 8; ++j) bfr[j] = *(const bf16x8*)(&Bs[bc][(j * 16 + ln) * 32 + cs]);
#pragma unroll
        for (int i = 0; i < 2; ++i)
#pragma unroll
            for (int j = 0; j < 8; ++j)
                acc[i][j] = __builtin_amdgcn_mfma_f32_16x16x32_bf16(af[i], bfr[j], acc[i][j], 0, 0, 0);
        bc = (bc == 2) ? 0 : bc + 1;
    }

    // ---- fused epilogue ----
    if (n0 < 2560) {
        bool isQ = (n0 < 2048);
        int h = isQ ? (n0 >> 7) : ((n0 - 2048) >> 7);
#pragma unroll
        for (int i = 0; i < 2; ++i)
#pragma unroll
            for (int r = 0; r < 4; ++r) {
                int row = m0 + wm + i * 16 + q * 4 + r;
                float y1[4], y2[4];
                float ss = 0.0f;
#pragma unroll
                for (int j = 0; j < 4; ++j) {
                    float a = acc[i][j][r];
                    float b = acc[i][j + 4][r];
                    float cc = cosb[row * 64 + j * 16 + ln];
                    float sv = sinb[row * 64 + j * 16 + ln];
                    y1[j] = a * cc + b * sv;
                    y2[j] = b * cc - a * sv;
                    ss += y1[j] * y1[j] + y2[j] * y2[j];
                }
                ss += __shfl_xor(ss, 1);
                ss += __shfl_xor(ss, 2);
                ss += __shfl_xor(ss, 4);
                ss += __shfl_xor(ss, 8);
                float rv = rsqrtf(ss * (1.0f / 128.0f) + 1e-6f);
                if (isQ) {
                    float s = rv * (0.08838834764831845f * 1.4426950408889634f);
                    unsigned short* ob = Qn + (size_t)row * 2048 + h * 128;
#pragma unroll
                    for (int j = 0; j < 4; ++j) {
                        ob[j * 16 + ln] = f2bf(y1[j] * s);
                        ob[64 + j * 16 + ln] = f2bf(y2[j] * s);
                    }
                } else {
                    unsigned short* ob = Kn + (size_t)row * 512 + h * 128;
#pragma unroll
                    for (int j = 0; j < 4; ++j) {
                        ob[j * 16 + ln] = f2bf(y1[j] * rv);
                        ob[64 + j * 16 + ln] = f2bf(y2[j] * rv);
                    }
                }
            }
    } else {
        // V: transpose via LDS scratch (pitch 136 shorts = 272B, 16B-aligned rows),
        // 2 halves of 64 cols. Scratch 8704 shorts fits in As[3] (12288 shorts).
        int v0 = n0 - 2560;
        unsigned short* sm = &As[0][0];
#pragma unroll
        for (int half = 0; half < 2; ++half) {
            __syncthreads();
#pragma unroll
            for (int i = 0; i < 2; ++i)
#pragma unroll
                for (int jj = 0; jj < 4; ++jj) {
                    int j = half * 4 + jj;
                    int cc = jj * 16 + ln;
                    int rr = wm + i * 16 + q * 4;
                    u16x4 pk;
                    pk.x = f2bf(acc[i][j][0]); pk.y = f2bf(acc[i][j][1]);
                    pk.z = f2bf(acc[i][j][2]); pk.w = f2bf(acc[i][j][3]);
                    *(u16x4*)(&sm[cc * 136 + rr]) = pk;
                }
            __syncthreads();
            // coalesced write out: 64 vt-rows x 128 m; each thread owns 32 shorts
            int vtr = t >> 2, mseg = (t & 3) * 32;
            unsigned short* dst = Vt + (size_t)(v0 + half * 64 + vtr) * 4096 + m0 + mseg;
            const unsigned short* src = &sm[vtr * 136 + mseg];
            *(int4*)(dst)      = *(const int4*)(src);
            *(int4*)(dst + 8)  = *(const int4*)(src + 8);
            *(int4*)(dst + 16) = *(const int4*)(src + 16);
            *(int4*)(dst + 24) = *(const int4*)(src + 24);
        }
    }
}

// ---------------- bf16 GEMM (out-proj): 128x128, BK=32, 3-buffer counted vmcnt ----------------
__global__ __launch_bounds__(256, 3) void gemm_bt_db(const unsigned short* __restrict__ A,
                                                     const unsigned short* __restrict__ Bt,
                                                     float* __restrict__ C, int M, int N, int K) {
    __shared__ __align__(16) unsigned short As[3][128 * 32];
    __shared__ __align__(16) unsigned short Bs[3][128 * 32];
    int t = threadIdx.x;
    int w = t >> 6, lane = t & 63;
    int ln = lane & 15, q = lane >> 4;
    int wm = (w >> 1) * 64, wn = (w & 1) * 64;
    int m0 = blockIdx.y * 128, n0 = blockIdx.x * 128;

    f32x4 acc[4][4] = {};

    auto stage = [&](int b, int k0) {
#pragma unroll
        for (int s = 0; s < 2; ++s) {
            int L = s * 256 + t;
            int r = L >> 2;
            int c = (L & 3) ^ ((L >> 4) & 3);
            async_cp16(&A[(size_t)(m0 + r) * K + k0 + c * 8], &As[b][s * 2048 + w * 512]);
            async_cp16(&Bt[(size_t)(n0 + r) * K + k0 + c * 8], &Bs[b][s * 2048 + w * 512]);
        }
    };

    stage(0, 0);
    stage(1, 32);

    int niter = K >> 5;
    int bc = 0;
    for (int it = 0; it < niter; ++it) {
        if (it < niter - 1) asm volatile("s_waitcnt vmcnt(4)" ::: "memory");
        else                asm volatile("s_waitcnt vmcnt(0)" ::: "memory");
        __builtin_amdgcn_s_barrier();
        __builtin_amdgcn_sched_barrier(0);
        if (it < niter - 2) {
            int bn = bc + 2; if (bn >= 3) bn -= 3;
            stage(bn, (it + 2) * 32);
        }
        int cs = (q ^ ((ln >> 2) & 3)) * 8;
        bf16x8 af[4], bfr[4];
#pragma unroll
        for (int i = 0; i < 4; ++i) af[i] = *(const bf16x8*)(&As[bc][(wm + i * 16 + ln) * 32 + cs]);
#pragma unroll
        for (int j = 0; j < 4; ++j) bfr[j] = *(const bf16x8*)(&Bs[bc][(wn + j * 16 + ln) * 32 + cs]);
#pragma unroll
        for (int i = 0; i < 4; ++i)
#pragma unroll
            for (int j = 0; j < 4; ++j)
                acc[i][j] = __builtin_amdgcn_mfma_f32_16x16x32_bf16(af[i], bfr[j], acc[i][j], 0, 0, 0);
        bc = (bc == 2) ? 0 : bc + 1;
    }
#pragma unroll
    for (int i = 0; i < 4; ++i)
#pragma unroll
        for (int j = 0; j < 4; ++j)
#pragma unroll
            for (int r = 0; r < 4; ++r) {
                int row = m0 + wm + i * 16 + q * 4 + r;
                int col = n0 + wn + j * 16 + ln;
                C[(size_t)row * N + col] = acc[i][j][r];
            }
}

// ---------------- Flash attention v4: fixed-max softmax (unchanged, known-good) ----------------
__global__ __launch_bounds__(256) void flash_attn(const unsigned short* __restrict__ Qn,
                                                  const unsigned short* __restrict__ Kn,
                                                  const unsigned short* __restrict__ Vt,
                                                  unsigned short* __restrict__ Ao) {
    __shared__ __align__(16) unsigned short Ks[2][64 * 128];
    __shared__ __align__(16) unsigned short Vs[2][128 * 64];
    __shared__ __align__(16) unsigned short Pl[4][16 * 72];

    int pairi = blockIdx.x;
    int h = blockIdx.y;
    int kvh = h >> 2;
    int t = threadIdx.x;
    int w = t >> 6, lane = t & 63;
    int ln = lane & 15, q = lane >> 4;

    int nA = 64 - pairi;
    int bq = 63 - pairi;
    int wq0 = bq * 64 + w * 16;

    bf16x8 qf[4];
    {
        const unsigned short* qb = Qn + (size_t)(wq0 + ln) * 2048 + h * 128;
#pragma unroll
        for (int kc = 0; kc < 4; ++kc) qf[kc] = *(const bf16x8*)(qb + kc * 32 + q * 8);
    }

    f32x4 o[8] = {};
    f32x4 l_p = {0.f, 0.f, 0.f, 0.f};

#pragma unroll
    for (int s = 0; s < 4; ++s) {
        int L = s * 256 + t;
        int key = L >> 4;
        int c = (L & 15) ^ (key & 15);
        async_cp16(Kn + (size_t)key * 512 + kvh * 128 + c * 8, &Ks[0][s * 2048 + w * 512]);
    }
#pragma unroll
    for (int s = 0; s < 4; ++s) {
        int L = s * 256 + t;
        int hd = L >> 3;
        int c = (L & 7) ^ (hd & 7);
        async_cp16(Vt + (size_t)(kvh * 128 + hd) * 4096 + c * 8, &Vs[0][s * 2048 + w * 512]);
    }

    for (int it = 0; it < 65; ++it) {
        __syncthreads();

        int nxt = it + 1;
        if (nxt < 65) {
            int nkt = (nxt < nA) ? nxt * 64 : (nxt - nA) * 64;
            unsigned short* kd = Ks[nxt & 1];
            unsigned short* vd = Vs[nxt & 1];
#pragma unroll
            for (int s = 0; s < 4; ++s) {
                int L = s * 256 + t;
                int key = L >> 4;
                int c = (L & 15) ^ (key & 15);
                async_cp16(Kn + (size_t)(nkt + key) * 512 + kvh * 128 + c * 8,
                           kd + s * 2048 + w * 512);
            }
#pragma unroll
            for (int s = 0; s < 4; ++s) {
                int L = s * 256 + t;
                int hd = L >> 3;
                int c = (L & 7) ^ (hd & 7);
                async_cp16(Vt + (size_t)(kvh * 128 + hd) * 4096 + nkt + c * 8,
                           vd + s * 2048 + w * 512);
            }
        }

        if (it == nA) {
#pragma unroll
            for (int r = 0; r < 4; ++r) {
                float lsum = l_p[r];
                lsum += __shfl_xor(lsum, 1);
                lsum += __shfl_xor(lsum, 2);
                lsum += __shfl_xor(lsum, 4);
                lsum += __shfl_xor(lsum, 8);
                float inv = 1.0f / lsum;
                int row = wq0 + q * 4 + r;
                unsigned short* ob = Ao + (size_t)row * 2048 + h * 128;
#pragma unroll
                for (int f = 0; f < 8; ++f) ob[f * 16 + ln] = f2bf(o[f][r] * inv);
            }
            bq = pairi;
            wq0 = bq * 64 + w * 16;
            const unsigned short* qb = Qn + (size_t)(wq0 + ln) * 2048 + h * 128;
#pragma unroll
            for (int kc = 0; kc < 4; ++kc) qf[kc] = *(const bf16x8*)(qb + kc * 32 + q * 8);
#pragma unroll
            for (int f = 0; f < 8; ++f) o[f] = (f32x4){0.f, 0.f, 0.f, 0.f};
            l_p = (f32x4){0.f, 0.f, 0.f, 0.f};
        }

        int kt0 = (it < nA) ? it * 64 : (it - nA) * 64;
        const unsigned short* kb = Ks[it & 1];
        const unsigned short* vb = Vs[it & 1];

        f32x4 sA[4] = {{-16.6f, -16.6f, -16.6f, -16.6f}, {-16.6f, -16.6f, -16.6f, -16.6f},
                       {-16.6f, -16.6f, -16.6f, -16.6f}, {-16.6f, -16.6f, -16.6f, -16.6f}};
#pragma unroll
        for (int jt = 0; jt < 4; ++jt) {
            int key = jt * 16 + ln;
#pragma unroll
            for (int kc = 0; kc < 4; ++kc) {
                int cs = ((kc * 4 + q) ^ ln) * 8;
                bf16x8 kf = *(const bf16x8*)(&kb[key * 128 + cs]);
                sA[jt] = __builtin_amdgcn_mfma_f32_16x16x32_bf16(qf[kc], kf, sA[jt], 0, 0, 0);
            }
        }
        if (kt0 + 63 > wq0) {
#pragma unroll
            for (int jt = 0; jt < 4; ++jt)
#pragma unroll
                for (int r = 0; r < 4; ++r) {
                    int key = kt0 + jt * 16 + ln;
                    int row = wq0 + q * 4 + r;
                    if (key > row) sA[jt][r] = -3e38f;
                }
        }
#pragma unroll
        for (int r = 0; r < 4; ++r) {
            int prow = (q * 4 + r) * 72;
#pragma unroll
            for (int jt = 0; jt < 4; ++jt) {
                float p = __builtin_amdgcn_exp2f(sA[jt][r]);
                Pl[w][prow + jt * 16 + ln] = (unsigned short)(__float_as_uint(p) >> 16);
                l_p[r] += p;
            }
        }

#pragma unroll
        for (int ks = 0; ks < 2; ++ks) {
            bf16x8 pa = *(const bf16x8*)(&Pl[w][ln * 72 + ks * 32 + q * 8]);
            int cs = ((ks * 4 + q) ^ (ln & 7)) * 8;
#pragma unroll
            for (int f = 0; f < 8; ++f) {
                bf16x8 vf = *(const bf16x8*)(&vb[(f * 16 + ln) * 64 + cs]);
                o[f] = __builtin_amdgcn_mfma_f32_16x16x32_bf16(pa, vf, o[f], 0, 0, 0);
            }
        }
    }
#pragma unroll
    for (int r = 0; r < 4; ++r) {
        float lsum = l_p[r];
        lsum += __shfl_xor(lsum, 1);
        lsum += __shfl_xor(lsum, 2);
        lsum += __shfl_xor(lsum, 4);
        lsum += __shfl_xor(lsum, 8);
        float inv = 1.0f / lsum;
        int row = wq0 + q * 4 + r;
        unsigned short* ob = Ao + (size_t)row * 2048 + h * 128;
#pragma unroll
        for (int f = 0; f < 8; ++f) ob[f * 16 + ln] = f2bf(o[f][r] * inv);
    }
}

extern "C" void kernel_launch(void* const* d_in, const int* in_sizes, int n_in,
                              void* d_out, int out_size, void* d_ws, size_t ws_size,
                              hipStream_t stream) {
    const float* x    = (const float*)d_in[0];
    const float* cosb = (const float*)d_in[1];
    const float* sinb = (const float*)d_in[2];
    const float* wq   = (const float*)d_in[3];
    const float* wk   = (const float*)d_in[4];
    const float* wv   = (const float*)d_in[5];
    const float* wo   = (const float*)d_in[6];
    float* out = (float*)d_out;

    char* ws = (char*)d_ws;
    unsigned short* xb    = (unsigned short*)ws;               // [4096][2048]
    unsigned short* wqkvT = xb    + (size_t)4096 * 2048;       // [3072][2048]
    unsigned short* woT   = wqkvT + (size_t)3072 * 2048;       // [2048][2048]
    unsigned short* Qn    = woT   + (size_t)2048 * 2048;       // [4096][2048]
    unsigned short* Kn    = Qn    + (size_t)4096 * 2048;       // [4096][512]
    unsigned short* Vt    = Kn    + (size_t)4096 * 512;        // [512][4096]
    unsigned short* Ao    = Vt    + (size_t)512 * 4096;        // [4096][2048]

    cvt_bf16<<<(4096 * 2048 / 4 + 255) / 256, 256, 0, stream>>>(x, xb, 4096 * 2048);
    transpose_all<<<dim3(64, 64, 4), dim3(32, 8), 0, stream>>>(wq, wk, wv, wo, wqkvT, woT);
    gemm_qkv<<<dim3(24, 32), 256, 0, stream>>>(xb, wqkvT, cosb, sinb, Qn, Kn, Vt);
    flash_attn<<<dim3(32, 16), 256, 0, stream>>>(Qn, Kn, Vt, Ao);
    gemm_bt_db<<<dim3(16, 32), 256, 0, stream>>>(Ao, woT, out, 4096, 2048, 2048);
}

// Round 5
// 350.405 us; speedup vs baseline: 1.0219x; 1.0219x over previous
//
#include <hip/hip_runtime.h>

#define T_SEQ 4096
#define C_EMB 2048
#define NH 16
#define NKV 4
#define HD 128

typedef short bf16x8 __attribute__((ext_vector_type(8)));
typedef float f32x4 __attribute__((ext_vector_type(4)));
typedef unsigned short u16x4 __attribute__((ext_vector_type(4)));

__device__ inline unsigned short f2bf(float f) {
    unsigned int u = __float_as_uint(f);
    unsigned int r = (u + 0x7FFFu + ((u >> 16) & 1u)) >> 16;
    return (unsigned short)r;
}

// async global->LDS 16B per lane; lds base must be wave-uniform (lane*16 auto-added)
__device__ __forceinline__ void async_cp16(const unsigned short* g, unsigned short* l) {
    __builtin_amdgcn_global_load_lds((const __attribute__((address_space(1))) unsigned int*)g,
                                     (__attribute__((address_space(3))) unsigned int*)l,
                                     16, 0, 0);
}

// ---------------- fp32 -> bf16 elementwise ----------------
__global__ __launch_bounds__(256) void cvt_bf16(const float* __restrict__ in,
                                                unsigned short* __restrict__ out, int n) {
    int i = (blockIdx.x * 256 + threadIdx.x) * 4;
    if (i >= n) return;
    float4 f = *(const float4*)(&in[i]);
    u16x4 o;
    o.x = f2bf(f.x); o.y = f2bf(f.y); o.z = f2bf(f.z); o.w = f2bf(f.w);
    *(u16x4*)(&out[i]) = o;
}

// ---------------- merged weight transposes: 4 matrices in one launch ----------------
__global__ __launch_bounds__(256) void transpose_all(const float* __restrict__ wq,
                                                     const float* __restrict__ wk,
                                                     const float* __restrict__ wv,
                                                     const float* __restrict__ wo,
                                                     unsigned short* __restrict__ wqkvT,
                                                     unsigned short* __restrict__ woT) {
    __shared__ float tile[32][33];
    int z = blockIdx.z;
    const float* in;
    unsigned short* out;
    int ld_in;
    if (z == 0)      { in = wq; out = wqkvT;                         ld_in = 2048; }
    else if (z == 1) { in = wk; out = wqkvT + (size_t)2048 * 2048;   ld_in = 512;  }
    else if (z == 2) { in = wv; out = wqkvT + (size_t)2560 * 2048;   ld_in = 512;  }
    else             { in = wo; out = woT;                           ld_in = 2048; }
    if ((z == 1 || z == 2) && blockIdx.x >= 16) return;

    int x = blockIdx.x * 32 + threadIdx.x;
    for (int i = threadIdx.y; i < 32; i += 8) {
        int y = blockIdx.y * 32 + i;
        tile[i][threadIdx.x] = in[(size_t)y * ld_in + x];
    }
    __syncthreads();
    int xo = blockIdx.y * 32 + threadIdx.x;
    for (int i = threadIdx.y; i < 32; i += 8) {
        int yo = blockIdx.x * 32 + i;
        out[(size_t)yo * 2048 + xo] = f2bf(tile[threadIdx.x][i]);
    }
}

// ==== Fused QKV projection + RoPE + RMSNorm + V-transpose ====
// v9: 128x128 tile, BK=32, 3-buffer counted vmcnt (as v8) + XCD-rectangle swizzle:
// each XCD owns an 8-row x 12-col tile rectangle so panel refetches hit its own L2
// instead of streaming from Infinity Cache (theory: GEMMs are L3-refetch-bound).
// Staging addresses hoisted to per-thread base pointers (mul -> add per iter).
__global__ __launch_bounds__(256, 3) void gemm_qkv(const unsigned short* __restrict__ A,
                                                   const unsigned short* __restrict__ Bt,
                                                   const float* __restrict__ cosb,
                                                   const float* __restrict__ sinb,
                                                   unsigned short* __restrict__ Qn,
                                                   unsigned short* __restrict__ Kn,
                                                   unsigned short* __restrict__ Vt) {
    __shared__ __align__(16) unsigned short As[3][128 * 32];
    __shared__ __align__(16) unsigned short Bs[3][128 * 32];
    const int K = 2048;
    int t = threadIdx.x;
    int w = t >> 6, lane = t & 63;
    int ln = lane & 15, q = lane >> 4;
    int wm = w * 32;

    // XCD-rectangle swizzle: grid 24x32 = 768 = 8 XCDs x (12 cols x 8 rows)
    int d = blockIdx.y * 24 + blockIdx.x;
    int xcd = d & 7, l = d >> 3;              // dispatch round-robins XCD = d%8
    int lx = l % 12, ly = l / 12;
    int bx = (xcd & 1) * 12 + lx;
    int by = (xcd >> 1) * 8 + ly;
    int m0 = by * 128, n0 = bx * 128;

    f32x4 acc[2][8] = {};

    // hoisted per-thread staging bases
    int r0 = t >> 2, c0 = (t & 3) ^ ((t >> 4) & 3);
    int L1 = 256 + t;
    int r1 = L1 >> 2, c1 = (L1 & 3) ^ ((L1 >> 4) & 3);
    const unsigned short* a0 = &A[(size_t)(m0 + r0) * K + c0 * 8];
    const unsigned short* a1 = &A[(size_t)(m0 + r1) * K + c1 * 8];
    const unsigned short* b0 = &Bt[(size_t)(n0 + r0) * K + c0 * 8];
    const unsigned short* b1 = &Bt[(size_t)(n0 + r1) * K + c1 * 8];

    auto stage = [&](int b, int k0) {
        async_cp16(a0 + k0, &As[b][w * 512]);
        async_cp16(a1 + k0, &As[b][2048 + w * 512]);
        async_cp16(b0 + k0, &Bs[b][w * 512]);
        async_cp16(b1 + k0, &Bs[b][2048 + w * 512]);
    };

    stage(0, 0);
    stage(1, 32);

    int bc = 0;
    for (int it = 0; it < 64; ++it) {
        // wait for own current-tile loads (4 newest = next tile may stay in flight)
        if (it < 63) asm volatile("s_waitcnt vmcnt(4)" ::: "memory");
        else         asm volatile("s_waitcnt vmcnt(0)" ::: "memory");
        __builtin_amdgcn_s_barrier();
        __builtin_amdgcn_sched_barrier(0);
        if (it < 62) {
            int bn = bc + 2; if (bn >= 3) bn -= 3;
            stage(bn, (it + 2) * 32);
        }
        int cs = (q ^ ((ln >> 2) & 3)) * 8;
        bf16x8 af[2], bfr[8];
#pragma unroll
        for (int i = 0; i < 2; ++i) af[i] = *(const bf16x8*)(&As[bc][(wm + i * 16 + ln) * 32 + cs]);
#pragma unroll
        for (int j = 0; j < 8; ++j) bfr[j] = *(const bf16x8*)(&Bs[bc][(j * 16 + ln) * 32 + cs]);
#pragma unroll
        for (int i = 0; i < 2; ++i)
#pragma unroll
            for (int j = 0; j < 8; ++j)
                acc[i][j] = __builtin_amdgcn_mfma_f32_16x16x32_bf16(af[i], bfr[j], acc[i][j], 0, 0, 0);
        bc = (bc == 2) ? 0 : bc + 1;
    }

    // ---- fused epilogue ----
    if (n0 < 2560) {
        bool isQ = (n0 < 2048);
        int h = isQ ? (n0 >> 7) : ((n0 - 2048) >> 7);
#pragma unroll
        for (int i = 0; i < 2; ++i)
#pragma unroll
            for (int r = 0; r < 4; ++r) {
                int row = m0 + wm + i * 16 + q * 4 + r;
                float y1[4], y2[4];
                float ss = 0.0f;
#pragma unroll
                for (int j = 0; j < 4; ++j) {
                    float a = acc[i][j][r];
                    float b = acc[i][j + 4][r];
                    float cc = cosb[row * 64 + j * 16 + ln];
                    float sv = sinb[row * 64 + j * 16 + ln];
                    y1[j] = a * cc + b * sv;
                    y2[j] = b * cc - a * sv;
                    ss += y1[j] * y1[j] + y2[j] * y2[j];
                }
                ss += __shfl_xor(ss, 1);
                ss += __shfl_xor(ss, 2);
                ss += __shfl_xor(ss, 4);
                ss += __shfl_xor(ss, 8);
                float rv = rsqrtf(ss * (1.0f / 128.0f) + 1e-6f);
                if (isQ) {
                    float s = rv * (0.08838834764831845f * 1.4426950408889634f);
                    unsigned short* ob = Qn + (size_t)row * 2048 + h * 128;
#pragma unroll
                    for (int j = 0; j < 4; ++j) {
                        ob[j * 16 + ln] = f2bf(y1[j] * s);
                        ob[64 + j * 16 + ln] = f2bf(y2[j] * s);
                    }
                } else {
                    unsigned short* ob = Kn + (size_t)row * 512 + h * 128;
#pragma unroll
                    for (int j = 0; j < 4; ++j) {
                        ob[j * 16 + ln] = f2bf(y1[j] * rv);
                        ob[64 + j * 16 + ln] = f2bf(y2[j] * rv);
                    }
                }
            }
    } else {
        // V: transpose via LDS scratch (pitch 136 shorts = 272B, 16B-aligned rows),
        // 2 halves of 64 cols. Scratch 8704 shorts fits in As[3] (12288 shorts).
        int v0 = n0 - 2560;
        unsigned short* sm = &As[0][0];
#pragma unroll
        for (int half = 0; half < 2; ++half) {
            __syncthreads();
#pragma unroll
            for (int i = 0; i < 2; ++i)
#pragma unroll
                for (int jj = 0; jj < 4; ++jj) {
                    int j = half * 4 + jj;
                    int cc = jj * 16 + ln;
                    int rr = wm + i * 16 + q * 4;
                    u16x4 pk;
                    pk.x = f2bf(acc[i][j][0]); pk.y = f2bf(acc[i][j][1]);
                    pk.z = f2bf(acc[i][j][2]); pk.w = f2bf(acc[i][j][3]);
                    *(u16x4*)(&sm[cc * 136 + rr]) = pk;
                }
            __syncthreads();
            // coalesced write out: 64 vt-rows x 128 m; each thread owns 32 shorts
            int vtr = t >> 2, mseg = (t & 3) * 32;
            unsigned short* dst = Vt + (size_t)(v0 + half * 64 + vtr) * 4096 + m0 + mseg;
            const unsigned short* src = &sm[vtr * 136 + mseg];
            *(int4*)(dst)      = *(const int4*)(src);
            *(int4*)(dst + 8)  = *(const int4*)(src + 8);
            *(int4*)(dst + 16) = *(const int4*)(src + 16);
            *(int4*)(dst + 24) = *(const int4*)(src + 24);
        }
    }
}

// ---------------- bf16 GEMM (out-proj): 128x128, BK=32, 3-buffer counted vmcnt ----------------
// + XCD-rectangle swizzle (grid 16x32 = 8 XCDs x (8 cols x 8 rows)), hoisted bases.
__global__ __launch_bounds__(256, 3) void gemm_bt_db(const unsigned short* __restrict__ A,
                                                     const unsigned short* __restrict__ Bt,
                                                     float* __restrict__ C, int M, int N, int K) {
    __shared__ __align__(16) unsigned short As[3][128 * 32];
    __shared__ __align__(16) unsigned short Bs[3][128 * 32];
    int t = threadIdx.x;
    int w = t >> 6, lane = t & 63;
    int ln = lane & 15, q = lane >> 4;
    int wm = (w >> 1) * 64, wn = (w & 1) * 64;

    int d = blockIdx.y * 16 + blockIdx.x;
    int xcd = d & 7, l = d >> 3;
    int lx = l & 7, ly = l >> 3;
    int bx = (xcd & 1) * 8 + lx;
    int by = (xcd >> 1) * 8 + ly;
    int m0 = by * 128, n0 = bx * 128;

    f32x4 acc[4][4] = {};

    int r0 = t >> 2, c0 = (t & 3) ^ ((t >> 4) & 3);
    int L1 = 256 + t;
    int r1 = L1 >> 2, c1 = (L1 & 3) ^ ((L1 >> 4) & 3);
    const unsigned short* a0 = &A[(size_t)(m0 + r0) * K + c0 * 8];
    const unsigned short* a1 = &A[(size_t)(m0 + r1) * K + c1 * 8];
    const unsigned short* b0 = &Bt[(size_t)(n0 + r0) * K + c0 * 8];
    const unsigned short* b1 = &Bt[(size_t)(n0 + r1) * K + c1 * 8];

    auto stage = [&](int b, int k0) {
        async_cp16(a0 + k0, &As[b][w * 512]);
        async_cp16(a1 + k0, &As[b][2048 + w * 512]);
        async_cp16(b0 + k0, &Bs[b][w * 512]);
        async_cp16(b1 + k0, &Bs[b][2048 + w * 512]);
    };

    stage(0, 0);
    stage(1, 32);

    int niter = K >> 5;
    int bc = 0;
    for (int it = 0; it < niter; ++it) {
        if (it < niter - 1) asm volatile("s_waitcnt vmcnt(4)" ::: "memory");
        else                asm volatile("s_waitcnt vmcnt(0)" ::: "memory");
        __builtin_amdgcn_s_barrier();
        __builtin_amdgcn_sched_barrier(0);
        if (it < niter - 2) {
            int bn = bc + 2; if (bn >= 3) bn -= 3;
            stage(bn, (it + 2) * 32);
        }
        int cs = (q ^ ((ln >> 2) & 3)) * 8;
        bf16x8 af[4], bfr[4];
#pragma unroll
        for (int i = 0; i < 4; ++i) af[i] = *(const bf16x8*)(&As[bc][(wm + i * 16 + ln) * 32 + cs]);
#pragma unroll
        for (int j = 0; j < 4; ++j) bfr[j] = *(const bf16x8*)(&Bs[bc][(wn + j * 16 + ln) * 32 + cs]);
#pragma unroll
        for (int i = 0; i < 4; ++i)
#pragma unroll
            for (int j = 0; j < 4; ++j)
                acc[i][j] = __builtin_amdgcn_mfma_f32_16x16x32_bf16(af[i], bfr[j], acc[i][j], 0, 0, 0);
        bc = (bc == 2) ? 0 : bc + 1;
    }
#pragma unroll
    for (int i = 0; i < 4; ++i)
#pragma unroll
        for (int j = 0; j < 4; ++j)
#pragma unroll
            for (int r = 0; r < 4; ++r) {
                int row = m0 + wm + i * 16 + q * 4 + r;
                int col = n0 + wn + j * 16 + ln;
                C[(size_t)row * N + col] = acc[i][j][r];
            }
}

// ---------------- Flash attention v4.1: v4 + setprio(T5) + hoisted staging bases ----------------
__global__ __launch_bounds__(256) void flash_attn(const unsigned short* __restrict__ Qn,
                                                  const unsigned short* __restrict__ Kn,
                                                  const unsigned short* __restrict__ Vt,
                                                  unsigned short* __restrict__ Ao) {
    __shared__ __align__(16) unsigned short Ks[2][64 * 128];
    __shared__ __align__(16) unsigned short Vs[2][128 * 64];
    __shared__ __align__(16) unsigned short Pl[4][16 * 72];

    int pairi = blockIdx.x;
    int h = blockIdx.y;
    int kvh = h >> 2;
    int t = threadIdx.x;
    int w = t >> 6, lane = t & 63;
    int ln = lane & 15, q = lane >> 4;

    int nA = 64 - pairi;
    int bq = 63 - pairi;
    int wq0 = bq * 64 + w * 16;

    bf16x8 qf[4];
    {
        const unsigned short* qb = Qn + (size_t)(wq0 + ln) * 2048 + h * 128;
#pragma unroll
        for (int kc = 0; kc < 4; ++kc) qf[kc] = *(const bf16x8*)(qb + kc * 32 + q * 8);
    }

    f32x4 o[8] = {};
    f32x4 l_p = {0.f, 0.f, 0.f, 0.f};

    // hoisted per-thread staging bases (key/hd/swizzle fixed per s)
    const unsigned short* kbase[4];
    const unsigned short* vbase[4];
#pragma unroll
    for (int s = 0; s < 4; ++s) {
        int L = s * 256 + t;
        int key = L >> 4;
        int ck = (L & 15) ^ (key & 15);
        kbase[s] = Kn + (size_t)key * 512 + kvh * 128 + ck * 8;
        int hd = L >> 3;
        int cv = (L & 7) ^ (hd & 7);
        vbase[s] = Vt + (size_t)(kvh * 128 + hd) * 4096 + cv * 8;
    }

#pragma unroll
    for (int s = 0; s < 4; ++s) async_cp16(kbase[s], &Ks[0][s * 2048 + w * 512]);
#pragma unroll
    for (int s = 0; s < 4; ++s) async_cp16(vbase[s], &Vs[0][s * 2048 + w * 512]);

    for (int it = 0; it < 65; ++it) {
        __syncthreads();

        int nxt = it + 1;
        if (nxt < 65) {
            int nkt = (nxt < nA) ? nxt * 64 : (nxt - nA) * 64;
            size_t koff = (size_t)nkt * 512;
            unsigned short* kd = Ks[nxt & 1];
            unsigned short* vd = Vs[nxt & 1];
#pragma unroll
            for (int s = 0; s < 4; ++s) async_cp16(kbase[s] + koff, kd + s * 2048 + w * 512);
#pragma unroll
            for (int s = 0; s < 4; ++s) async_cp16(vbase[s] + nkt, vd + s * 2048 + w * 512);
        }

        if (it == nA) {
#pragma unroll
            for (int r = 0; r < 4; ++r) {
                float lsum = l_p[r];
                lsum += __shfl_xor(lsum, 1);
                lsum += __shfl_xor(lsum, 2);
                lsum += __shfl_xor(lsum, 4);
                lsum += __shfl_xor(lsum, 8);
                float inv = 1.0f / lsum;
                int row = wq0 + q * 4 + r;
                unsigned short* ob = Ao + (size_t)row * 2048 + h * 128;
#pragma unroll
                for (int f = 0; f < 8; ++f) ob[f * 16 + ln] = f2bf(o[f][r] * inv);
            }
            bq = pairi;
            wq0 = bq * 64 + w * 16;
            const unsigned short* qb = Qn + (size_t)(wq0 + ln) * 2048 + h * 128;
#pragma unroll
            for (int kc = 0; kc < 4; ++kc) qf[kc] = *(const bf16x8*)(qb + kc * 32 + q * 8);
#pragma unroll
            for (int f = 0; f < 8; ++f) o[f] = (f32x4){0.f, 0.f, 0.f, 0.f};
            l_p = (f32x4){0.f, 0.f, 0.f, 0.f};
        }

        int kt0 = (it < nA) ? it * 64 : (it - nA) * 64;
        const unsigned short* kb = Ks[it & 1];
        const unsigned short* vb = Vs[it & 1];

        f32x4 sA[4] = {{-16.6f, -16.6f, -16.6f, -16.6f}, {-16.6f, -16.6f, -16.6f, -16.6f},
                       {-16.6f, -16.6f, -16.6f, -16.6f}, {-16.6f, -16.6f, -16.6f, -16.6f}};
        __builtin_amdgcn_s_setprio(1);
#pragma unroll
        for (int jt = 0; jt < 4; ++jt) {
            int key = jt * 16 + ln;
#pragma unroll
            for (int kc = 0; kc < 4; ++kc) {
                int cs = ((kc * 4 + q) ^ ln) * 8;
                bf16x8 kf = *(const bf16x8*)(&kb[key * 128 + cs]);
                sA[jt] = __builtin_amdgcn_mfma_f32_16x16x32_bf16(qf[kc], kf, sA[jt], 0, 0, 0);
            }
        }
        __builtin_amdgcn_s_setprio(0);
        if (kt0 + 63 > wq0) {
#pragma unroll
            for (int jt = 0; jt < 4; ++jt)
#pragma unroll
                for (int r = 0; r < 4; ++r) {
                    int key = kt0 + jt * 16 + ln;
                    int row = wq0 + q * 4 + r;
                    if (key > row) sA[jt][r] = -3e38f;
                }
        }
#pragma unroll
        for (int r = 0; r < 4; ++r) {
            int prow = (q * 4 + r) * 72;
#pragma unroll
            for (int jt = 0; jt < 4; ++jt) {
                float p = __builtin_amdgcn_exp2f(sA[jt][r]);
                Pl[w][prow + jt * 16 + ln] = (unsigned short)(__float_as_uint(p) >> 16);
                l_p[r] += p;
            }
        }

        __builtin_amdgcn_s_setprio(1);
#pragma unroll
        for (int ks = 0; ks < 2; ++ks) {
            bf16x8 pa = *(const bf16x8*)(&Pl[w][ln * 72 + ks * 32 + q * 8]);
            int cs = ((ks * 4 + q) ^ (ln & 7)) * 8;
#pragma unroll
            for (int f = 0; f < 8; ++f) {
                bf16x8 vf = *(const bf16x8*)(&vb[(f * 16 + ln) * 64 + cs]);
                o[f] = __builtin_amdgcn_mfma_f32_16x16x32_bf16(pa, vf, o[f], 0, 0, 0);
            }
        }
        __builtin_amdgcn_s_setprio(0);
    }
#pragma unroll
    for (int r = 0; r < 4; ++r) {
        float lsum = l_p[r];
        lsum += __shfl_xor(lsum, 1);
        lsum += __shfl_xor(lsum, 2);
        lsum += __shfl_xor(lsum, 4);
        lsum += __shfl_xor(lsum, 8);
        float inv = 1.0f / lsum;
        int row = wq0 + q * 4 + r;
        unsigned short* ob = Ao + (size_t)row * 2048 + h * 128;
#pragma unroll
        for (int f = 0; f < 8; ++f) ob[f * 16 + ln] = f2bf(o[f][r] * inv);
    }
}

extern "C" void kernel_launch(void* const* d_in, const int* in_sizes, int n_in,
                              void* d_out, int out_size, void* d_ws, size_t ws_size,
                              hipStream_t stream) {
    const float* x    = (const float*)d_in[0];
    const float* cosb = (const float*)d_in[1];
    const float* sinb = (const float*)d_in[2];
    const float* wq   = (const float*)d_in[3];
    const float* wk   = (const float*)d_in[4];
    const float* wv   = (const float*)d_in[5];
    const float* wo   = (const float*)d_in[6];
    float* out = (float*)d_out;

    char* ws = (char*)d_ws;
    unsigned short* xb    = (unsigned short*)ws;               // [4096][2048]
    unsigned short* wqkvT = xb    + (size_t)4096 * 2048;       // [3072][2048]
    unsigned short* woT   = wqkvT + (size_t)3072 * 2048;       // [2048][2048]
    unsigned short* Qn    = woT   + (size_t)2048 * 2048;       // [4096][2048]
    unsigned short* Kn    = Qn    + (size_t)4096 * 2048;       // [4096][512]
    unsigned short* Vt    = Kn    + (size_t)4096 * 512;        // [512][4096]
    unsigned short* Ao    = Vt    + (size_t)512 * 4096;        // [4096][2048]

    cvt_bf16<<<(4096 * 2048 / 4 + 255) / 256, 256, 0, stream>>>(x, xb, 4096 * 2048);
    transpose_all<<<dim3(64, 64, 4), dim3(32, 8), 0, stream>>>(wq, wk, wv, wo, wqkvT, woT);
    gemm_qkv<<<dim3(24, 32), 256, 0, stream>>>(xb, wqkvT, cosb, sinb, Qn, Kn, Vt);
    flash_attn<<<dim3(32, 16), 256, 0, stream>>>(Qn, Kn, Vt, Ao);
    gemm_bt_db<<<dim3(16, 32), 256, 0, stream>>>(Ao, woT, out, 4096, 2048, 2048);
}